// Round 5
// baseline (167.446 us; speedup 1.0000x reference)
//
#include <hip/hip_runtime.h>
#include <hip/hip_bf16.h>
#include <math.h>

typedef short bf16x8 __attribute__((ext_vector_type(8)));
typedef float f32x4 __attribute__((ext_vector_type(4)));
typedef unsigned int u32x4 __attribute__((ext_vector_type(4)));
typedef unsigned int u32x2 __attribute__((ext_vector_type(2)));

#define SEQ 2048
#define MD 1024
#define DH 128

__device__ __forceinline__ unsigned f2b(float f) {
  union { __hip_bfloat16 h; unsigned short u; } c;
  c.h = __float2bfloat16(f);
  return (unsigned)c.u;
}

// async global->LDS, 16B per lane. LDS dest = wave-uniform base + lane*16.
__device__ __forceinline__ void cp16(void* lds_base, const void* gsrc) {
  __builtin_amdgcn_global_load_lds(
      (const __attribute__((address_space(1))) unsigned int*)gsrc,
      (__attribute__((address_space(3))) unsigned int*)lds_base, 16, 0, 0);
}

// ---------------------------------------------------------------------------
// W prep: W[1024][128] f32 -> Wt[128][1024] bf16 per proj (LDS transpose).
// ---------------------------------------------------------------------------
__global__ __launch_bounds__(256) void wprep_kernel(
    const float* __restrict__ wq, const float* __restrict__ wk,
    const float* __restrict__ wv, __hip_bfloat16* __restrict__ wt)
{
  const int proj = blockIdx.x;   // 3
  const int part = blockIdx.y;   // 8 k-slabs of 128
  const float* __restrict__ w = (proj == 0) ? wq : ((proj == 1) ? wk : wv);
  __hip_bfloat16* __restrict__ o = wt + (size_t)proj * (128 * 1024);
  __shared__ __hip_bfloat16 t[128 * 130];
  const int tid = threadIdx.x;
#pragma unroll 4
  for (int i = 0; i < 64; ++i) {
    int idx = i * 256 + tid;
    int kl = idx >> 7, n = idx & 127;
    t[kl * 130 + n] = __float2bfloat16(w[(size_t)(part * 128 + kl) * 128 + n]);
  }
  __syncthreads();
#pragma unroll 4
  for (int j = 0; j < 64; ++j) {
    int idx = j * 256 + tid;
    int n = idx >> 7, kl = idx & 127;
    o[(size_t)n * 1024 + part * 128 + kl] = t[kl * 130 + n];
  }
}

// ---------------------------------------------------------------------------
// Projection GEMM v3 (m97-style): X[16384,1024] f32 x Wt[128][1024] bf16.
// M=32 x N=128 tile, BK=64, 256 threads (4 waves 2x2: 16 rows x 64 cols).
// A staged f32 via global_load_lds (8KB single buffer, linear LDS,
// involutive XOR pre-swizzle on the GLOBAL source + same XOR on read).
// B = Wt fragments loaded straight from L2 to registers (no staging).
// grid (512, 3) = 1536 blocks -> 6 blocks/CU, 24 waves/CU.
// ---------------------------------------------------------------------------
__global__ __launch_bounds__(256) void proj_kernel(
    const float* __restrict__ xq, const float* __restrict__ xk, const float* __restrict__ xv,
    const __hip_bfloat16* __restrict__ wt,
    __hip_bfloat16* __restrict__ q_ws, __hip_bfloat16* __restrict__ k_ws,
    __hip_bfloat16* __restrict__ vt_ws)
{
  const int proj = blockIdx.y;
  const float* __restrict__ x = (proj == 0) ? xq : ((proj == 1) ? xk : xv);
  const __hip_bfloat16* __restrict__ w = wt + (size_t)proj * (128 * 1024);
  const int m0 = blockIdx.x * 32;
  const int tid = threadIdx.x;
  const int lane = tid & 63;
  const int wid = tid >> 6;
  const int ll = lane & 15, lh = lane >> 4;
  const int wr = (wid >> 1) * 16;   // wave row offset (0/16)
  const int wc = (wid & 1) * 64;    // wave col offset (0/64)

  __shared__ float Af[32 * 64];     // [row][k] f32, linear (gl_lds dest)
  char* Afb = (char*)Af;

  const f32x4 zero4 = {0.f, 0.f, 0.f, 0.f};
  f32x4 acc[4];
#pragma unroll
  for (int nf = 0; nf < 4; ++nf) acc[nf] = zero4;

  // staging: 8KB = 8 x 1KB wave-insts; wave w does chunks {2w, 2w+1}.
  // chunk c: linear LDS offset o = c*1024 + lane*16 -> row = o>>8,
  // slot = (o>>4)&15; global source slot pre-swizzled: slot ^ (row&15).
  int srow[2], scol[2];
#pragma unroll
  for (int c = 0; c < 2; ++c) {
    int o = (wid * 2 + c) * 1024 + lane * 16;
    int row = o >> 8;
    int slot = (o >> 4) & 15;
    srow[c] = row;
    scol[c] = (slot ^ (row & 15)) << 2;   // f32 index within k-tile
  }
  const int r = wr + ll;                   // A fragment row for this lane
  const int rsw = (r & 15);                // read-side XOR

  // B fragment base pointers (L2-resident Wt rows)
  const __hip_bfloat16* __restrict__ wb[4];
#pragma unroll
  for (int nf = 0; nf < 4; ++nf)
    wb[nf] = w + (size_t)(wc + nf * 16 + ll) * MD + lh * 8;

  for (int kt = 0; kt < 16; ++kt) {
    // ---- stage A tile [32][64] f32 via global_load_lds ----
    cp16(Afb + (wid * 2 + 0) * 1024,
         &x[(size_t)(m0 + srow[0]) * MD + kt * 64 + scol[0]]);
    cp16(Afb + (wid * 2 + 1) * 1024,
         &x[(size_t)(m0 + srow[1]) * MD + kt * 64 + scol[1]]);
    asm volatile("s_waitcnt vmcnt(0)" ::: "memory");
    __syncthreads();

    // ---- compute: 2 k-slices of 32 ----
#pragma unroll
    for (int kk = 0; kk < 2; ++kk) {
      const int s0 = kk * 8 + lh * 2;
      f32x4 a0 = *reinterpret_cast<f32x4*>(
          Afb + r * 256 + (((s0    ) ^ rsw) << 4));
      f32x4 a1 = *reinterpret_cast<f32x4*>(
          Afb + r * 256 + (((s0 + 1) ^ rsw) << 4));
      bf16x8 af;
#pragma unroll
      for (int j = 0; j < 4; ++j) {
        af[j]     = (short)f2b(a0[j]);
        af[4 + j] = (short)f2b(a1[j]);
      }
#pragma unroll
      for (int nf = 0; nf < 4; ++nf) {
        bf16x8 bv = *reinterpret_cast<const bf16x8*>(wb[nf] + kt * 64 + kk * 32);
        acc[nf] = __builtin_amdgcn_mfma_f32_16x16x32_bf16(af, bv, acc[nf], 0, 0, 0);
      }
    }
    __syncthreads();
  }

  // ---- epilogue ----
  if (proj < 2) {
    __hip_bfloat16* __restrict__ outp = proj ? k_ws : q_ws;
#pragma unroll
    for (int nf = 0; nf < 4; ++nf) {
      int col = wc + nf * 16 + ll;
#pragma unroll
      for (int q = 0; q < 4; ++q) {
        int row = m0 + wr + lh * 4 + q;
        union { __hip_bfloat16 h; unsigned short u; } c;
        c.u = (unsigned short)f2b(acc[nf][q]);
        outp[(size_t)row * DH + col] = c.h;
      }
    }
  } else {
    // V transposed: vt[b][d][s], 4 consecutive s per lane -> 8B store
    const int b = m0 >> 11, sb = m0 & 2047;
#pragma unroll
    for (int nf = 0; nf < 4; ++nf) {
      int s = sb + wr + lh * 4;
      int d = wc + nf * 16 + ll;
      u32x2 pk;
      pk[0] = f2b(acc[nf][0]) | (f2b(acc[nf][1]) << 16);
      pk[1] = f2b(acc[nf][2]) | (f2b(acc[nf][3]) << 16);
      *reinterpret_cast<u32x2*>(&vt_ws[((size_t)b * DH + d) * SEQ + s]) = pk;
    }
  }
}

// ---------------------------------------------------------------------------
// Split-KV causal flash attention (unchanged from Round 4).
// QBLK=64 (4 waves x 16 rows), KVBLK=64, chunk = 8 iters (512 kv).
// grid (80, 8) = 640 blocks; writes unnormalized partials.
// ---------------------------------------------------------------------------
__global__ __launch_bounds__(256) void attn_kernel(
    const __hip_bfloat16* __restrict__ q_ws, const __hip_bfloat16* __restrict__ k_ws,
    const __hip_bfloat16* __restrict__ vt_ws,
    float* __restrict__ pO, float* __restrict__ pml)
{
  const int s = blockIdx.x;
  int qt, c;
  if (s < 8)       { qt = s;                c = 0; }
  else if (s < 24) { int u = s - 8;  qt = 8 + (u >> 1);  c = u & 1; }
  else if (s < 48) { int u = s - 24; qt = 16 + u / 3;    c = u % 3; }
  else             { int u = s - 48; qt = 24 + (u >> 2); c = u & 3; }
  const int b = blockIdx.y;
  const int g = qt >> 3;
  const int slot = b * 80 + (4 * g * (g + 1) + (g + 1) * (qt & 7)) + c;

  const int tid = threadIdx.x;
  const int lane = tid & 63;
  const int wid = tid >> 6;
  const int ll = lane & 15;
  const int lh = lane >> 4;

  __shared__ __hip_bfloat16 Ks[64 * 128];
  __shared__ __hip_bfloat16 Vs[128 * 64];
  __shared__ float Ps[64 * 64];
  char* Ksb = (char*)Ks;
  char* Vsb = (char*)Vs;
  char* Psb = (char*)Ps;

  bf16x8 qf[4];
  {
    const size_t qbase = ((size_t)b * SEQ + qt * 64 + wid * 16 + ll) * DH;
#pragma unroll
    for (int kk = 0; kk < 4; ++kk)
      qf[kk] = *reinterpret_cast<const bf16x8*>(&q_ws[qbase + kk * 32 + lh * 8]);
  }

  const f32x4 zero4 = {0.f, 0.f, 0.f, 0.f};
  float m_r[4], l_r[4];
  f32x4 oacc[8];
#pragma unroll
  for (int q = 0; q < 4; ++q) { m_r[q] = -INFINITY; l_r[q] = 0.f; }
#pragma unroll
  for (int nd = 0; nd < 8; ++nd) oacc[nd] = zero4;

  const float sl2e = 0.0883883476483184f * 1.4426950408889634f;

  const int it0 = c * 8;
  const int it1 = min(qt + 1, it0 + 8);
  for (int it = it0; it < it1; ++it) {
    const int kv0 = it * 64;
#pragma unroll
    for (int i = 0; i < 4; ++i) {
      int id = tid + i * 256;
      int row = id >> 4;
      int cb = (id & 15) << 4;
      u32x4 v = *reinterpret_cast<const u32x4*>(
          &k_ws[((size_t)b * SEQ + kv0 + row) * DH + (cb >> 1)]);
      *reinterpret_cast<u32x4*>(Ksb + row * 256 + (cb ^ ((row & 7) << 4))) = v;
    }
#pragma unroll
    for (int i = 0; i < 4; ++i) {
      int id = tid + i * 256;
      int d = id >> 3;
      int cb = (id & 7) << 4;
      u32x4 v = *reinterpret_cast<const u32x4*>(
          &vt_ws[((size_t)b * DH + d) * SEQ + kv0 + (cb >> 1)]);
      *reinterpret_cast<u32x4*>(Vsb + d * 128 + (cb ^ ((d & 7) << 4))) = v;
    }
    __syncthreads();

    f32x4 sacc[4];
#pragma unroll
    for (int nf = 0; nf < 4; ++nf) sacc[nf] = zero4;
#pragma unroll
    for (int nf = 0; nf < 4; ++nf) {
      int row = nf * 16 + ll;
#pragma unroll
      for (int kk = 0; kk < 4; ++kk) {
        bf16x8 kf = *reinterpret_cast<bf16x8*>(
            Ksb + row * 256 + ((kk * 64 + lh * 16) ^ ((row & 7) << 4)));
        sacc[nf] = __builtin_amdgcn_mfma_f32_16x16x32_bf16(qf[kk], kf, sacc[nf], 0, 0, 0);
      }
    }

    float sv[4][4];
    const int qr0 = qt * 64 + wid * 16 + lh * 4;
#pragma unroll
    for (int nf = 0; nf < 4; ++nf) {
      int kc = kv0 + nf * 16 + ll;
#pragma unroll
      for (int q = 0; q < 4; ++q) {
        float sc = sacc[nf][q] * sl2e;
        sv[nf][q] = (kc <= qr0 + q) ? sc : -INFINITY;
      }
    }

    float p[4][4];
    float alpha[4];
#pragma unroll
    for (int q = 0; q < 4; ++q) {
      float mx = fmaxf(fmaxf(sv[0][q], sv[1][q]), fmaxf(sv[2][q], sv[3][q]));
#pragma unroll
      for (int off = 1; off < 16; off <<= 1)
        mx = fmaxf(mx, __shfl_xor(mx, off));
      float mnew = fmaxf(m_r[q], mx);
      float sum = 0.f;
#pragma unroll
      for (int nf = 0; nf < 4; ++nf) {
        float pv = exp2f(sv[nf][q] - mnew);
        p[nf][q] = pv;
        sum += pv;
      }
#pragma unroll
      for (int off = 1; off < 16; off <<= 1)
        sum += __shfl_xor(sum, off);
      alpha[q] = exp2f(m_r[q] - mnew);
      l_r[q] = l_r[q] * alpha[q] + sum;
      m_r[q] = mnew;
    }
#pragma unroll
    for (int nd = 0; nd < 8; ++nd)
#pragma unroll
      for (int q = 0; q < 4; ++q) oacc[nd][q] *= alpha[q];

#pragma unroll
    for (int nf = 0; nf < 4; ++nf) {
      int kv = nf * 16 + ll;
      f32x4 pv4 = {p[nf][0], p[nf][1], p[nf][2], p[nf][3]};
      *reinterpret_cast<f32x4*>(
          Psb + kv * 256 + ((wid * 64 + lh * 16) ^ ((kv & 7) << 4))) = pv4;
    }

#pragma unroll
    for (int kf = 0; kf < 2; ++kf) {
      float pf[8];
#pragma unroll
      for (int j = 0; j < 8; ++j) {
        int kv = kf * 32 + lh * 8 + j;
        pf[j] = *reinterpret_cast<float*>(
            Psb + kv * 256 + ((wid * 64 + ll * 4) ^ ((kv & 7) << 4)));
      }
      bf16x8 pa;
#pragma unroll
      for (int j = 0; j < 8; ++j) pa[j] = (short)f2b(pf[j]);
#pragma unroll
      for (int nd = 0; nd < 8; ++nd) {
        int d = nd * 16 + ll;
        bf16x8 vf = *reinterpret_cast<bf16x8*>(
            Vsb + d * 128 + ((kf * 64 + lh * 16) ^ ((d & 7) << 4)));
        oacc[nd] = __builtin_amdgcn_mfma_f32_16x16x32_bf16(pa, vf, oacc[nd], 0, 0, 0);
      }
    }
    __syncthreads();
  }

  float* __restrict__ po = pO + (size_t)slot * (64 * 128);
#pragma unroll
  for (int nd = 0; nd < 8; ++nd) {
    int d = nd * 16 + ll;
#pragma unroll
    for (int q = 0; q < 4; ++q) {
      int row = wid * 16 + lh * 4 + q;
      po[row * 128 + d] = oacc[nd][q];
    }
  }
  if (ll == 0) {
    float* __restrict__ pm = pml + (size_t)slot * 128;
#pragma unroll
    for (int q = 0; q < 4; ++q) {
      int row = wid * 16 + lh * 4 + q;
      pm[row * 2 + 0] = m_r[q];
      pm[row * 2 + 1] = l_r[q];
    }
  }
}

// ---------------------------------------------------------------------------
// Combine: merge <=4 partials per (b, qt) with log-sum-exp weights.
// ---------------------------------------------------------------------------
__global__ __launch_bounds__(256) void combine_kernel(
    const float* __restrict__ pO, const float* __restrict__ pml,
    float* __restrict__ out)
{
  const int qt = blockIdx.x;
  const int b = blockIdx.y;
  const int g = qt >> 3;
  const int nc = g + 1;
  const size_t slot0 = (size_t)b * 80 + (4 * g * (g + 1) + (g + 1) * (qt & 7));
  const int tid = threadIdx.x;
  const int r = tid >> 2;
  const int q4 = tid & 3;

  float m[4], l[4];
#pragma unroll
  for (int i = 0; i < 4; ++i) {
    if (i < nc) {
      m[i] = pml[(slot0 + i) * 128 + r * 2 + 0];
      l[i] = pml[(slot0 + i) * 128 + r * 2 + 1];
    } else { m[i] = -INFINITY; l[i] = 0.f; }
  }
  float M = fmaxf(fmaxf(m[0], m[1]), fmaxf(m[2], m[3]));
  float w[4];
  float L = 0.f;
#pragma unroll
  for (int i = 0; i < 4; ++i) {
    w[i] = (i < nc) ? exp2f(m[i] - M) : 0.f;
    L += l[i] * w[i];
  }
  const float inv = 1.0f / L;

  const size_t orow = ((size_t)b * SEQ + qt * 64 + r) * DH;
#pragma unroll
  for (int j = 0; j < 8; ++j) {
    const int col = q4 * 32 + j * 4;
    f32x4 acc = {0.f, 0.f, 0.f, 0.f};
#pragma unroll
    for (int i = 0; i < 4; ++i) {
      if (i < nc) {
        f32x4 v = *reinterpret_cast<const f32x4*>(
            &pO[(slot0 + i) * (64 * 128) + r * 128 + col]);
#pragma unroll
        for (int u = 0; u < 4; ++u) acc[u] += v[u] * w[i];
      }
    }
#pragma unroll
    for (int u = 0; u < 4; ++u) acc[u] *= inv;
    *reinterpret_cast<f32x4*>(&out[orow + col]) = acc;
  }
}

extern "C" void kernel_launch(void* const* d_in, const int* in_sizes, int n_in,
                              void* d_out, int out_size, void* d_ws, size_t ws_size,
                              hipStream_t stream) {
  const float* xq = (const float*)d_in[0];
  const float* xk = (const float*)d_in[1];
  const float* xv = (const float*)d_in[2];
  const float* wq = (const float*)d_in[3];
  const float* wk = (const float*)d_in[4];
  const float* wv = (const float*)d_in[5];

  __hip_bfloat16* q_ws = (__hip_bfloat16*)d_ws;
  __hip_bfloat16* k_ws = q_ws + (size_t)16384 * 128;
  __hip_bfloat16* vt_ws = k_ws + (size_t)16384 * 128;
  __hip_bfloat16* wt_ws = vt_ws + (size_t)16384 * 128;
  float* pO = (float*)((char*)d_ws + 13369344);             // 640*64*128 f32
  float* pml = (float*)((char*)d_ws + 13369344 + 20971520); // 640*64*2 f32
  float* out = (float*)d_out;

  wprep_kernel<<<dim3(3, 8), 256, 0, stream>>>(wq, wk, wv, wt_ws);
  proj_kernel<<<dim3(512, 3), 256, 0, stream>>>(xq, xk, xv, wt_ws,
                                                q_ws, k_ws, vt_ws);
  attn_kernel<<<dim3(80, 8), 256, 0, stream>>>(q_ws, k_ws, vt_ws, pO, pml);
  combine_kernel<<<dim3(32, 8), 256, 0, stream>>>(pO, pml, out);
}

// Round 6
// 123.198 us; speedup vs baseline: 1.3592x; 1.3592x over previous
//
#include <hip/hip_runtime.h>
#include <hip/hip_bf16.h>
#include <math.h>

typedef short bf16x8 __attribute__((ext_vector_type(8)));
typedef float f32x4 __attribute__((ext_vector_type(4)));
typedef unsigned int u32x4 __attribute__((ext_vector_type(4)));
typedef unsigned int u32x2 __attribute__((ext_vector_type(2)));

#define SEQ 2048
#define MD 1024
#define DH 128

__device__ __forceinline__ unsigned f2b(float f) {
  union { __hip_bfloat16 h; unsigned short u; } c;
  c.h = __float2bfloat16(f);
  return (unsigned)c.u;
}

// async global->LDS, 16B per lane. LDS dest = wave-uniform base + lane*16.
__device__ __forceinline__ void cp16(void* lds_base, const void* gsrc) {
  __builtin_amdgcn_global_load_lds(
      (const __attribute__((address_space(1))) unsigned int*)gsrc,
      (__attribute__((address_space(3))) unsigned int*)lds_base, 16, 0, 0);
}

// ---------------------------------------------------------------------------
// W prep: W[1024][128] f32 -> Wt[128][1024] bf16 per proj (LDS transpose).
// ---------------------------------------------------------------------------
__global__ __launch_bounds__(256) void wprep_kernel(
    const float* __restrict__ wq, const float* __restrict__ wk,
    const float* __restrict__ wv, __hip_bfloat16* __restrict__ wt)
{
  const int proj = blockIdx.x;   // 3
  const int part = blockIdx.y;   // 8 k-slabs of 128
  const float* __restrict__ w = (proj == 0) ? wq : ((proj == 1) ? wk : wv);
  __hip_bfloat16* __restrict__ o = wt + (size_t)proj * (128 * 1024);
  __shared__ __hip_bfloat16 t[128 * 130];
  const int tid = threadIdx.x;
#pragma unroll 4
  for (int i = 0; i < 64; ++i) {
    int idx = i * 256 + tid;
    int kl = idx >> 7, n = idx & 127;
    t[kl * 130 + n] = __float2bfloat16(w[(size_t)(part * 128 + kl) * 128 + n]);
  }
  __syncthreads();
#pragma unroll 4
  for (int j = 0; j < 64; ++j) {
    int idx = j * 256 + tid;
    int n = idx >> 7, kl = idx & 127;
    o[(size_t)n * 1024 + part * 128 + kl] = t[kl * 130 + n];
  }
}

// ---------------------------------------------------------------------------
// Projection GEMM v4: X[16384,1024] f32 x Wt[128][1024] bf16 -> bf16.
// M=64 x N=128, BK=64, 4 waves (2x2 of 32rows x 64cols), grid (256,3).
// A: f32 staged via global_load_lds into DOUBLE-buffered LDS (16KB x2),
//    involutive XOR source-pre-swizzle (proven correct in R5), counted
//    vmcnt(12) + raw s_barrier so next tile's loads fly across barriers.
// B: Wt fragments register-prefetched one iter ahead straight from L2.
// ---------------------------------------------------------------------------
__global__ __launch_bounds__(256, 3) void proj_kernel(
    const float* __restrict__ xq, const float* __restrict__ xk, const float* __restrict__ xv,
    const __hip_bfloat16* __restrict__ wt,
    __hip_bfloat16* __restrict__ q_ws, __hip_bfloat16* __restrict__ k_ws,
    __hip_bfloat16* __restrict__ vt_ws)
{
  const int proj = blockIdx.y;
  const float* __restrict__ x = (proj == 0) ? xq : ((proj == 1) ? xk : xv);
  const __hip_bfloat16* __restrict__ w = wt + (size_t)proj * (128 * 1024);
  const int m0 = blockIdx.x * 64;
  const int tid = threadIdx.x;
  const int lane = tid & 63;
  const int wid = tid >> 6;
  const int ll = lane & 15, lh = lane >> 4;
  const int wr = (wid >> 1) * 32;   // wave row offset (0/32)
  const int wc = (wid & 1) * 64;    // wave col offset (0/64)

  __shared__ char lds[2][16 * 1024];  // A f32 [64 rows][256B], linear dest

  const f32x4 zero4 = {0.f, 0.f, 0.f, 0.f};
  f32x4 acc[2][4];
#pragma unroll
  for (int mi = 0; mi < 2; ++mi)
#pragma unroll
    for (int nf = 0; nf < 4; ++nf) acc[mi][nf] = zero4;

  // A staging map: 16 x 1KB wave-insts; wave w does chunks c*4+wid, c=0..3.
  // linear LDS off o -> row = o>>8, slot = (o>>4)&15; source slot ^= row&15.
  const float* __restrict__ asrc[4];
  int abase[4];
#pragma unroll
  for (int c = 0; c < 4; ++c) {
    int o = (c * 4 + wid) * 1024 + lane * 16;
    int row = o >> 8;
    int col = ((((o >> 4) & 15) ^ (row & 15)) << 2);
    asrc[c] = x + (size_t)(m0 + row) * MD + col;
    abase[c] = (c * 4 + wid) * 1024;
  }

  // B fragment base pointers (L2-resident Wt rows)
  const __hip_bfloat16* __restrict__ wb[4];
#pragma unroll
  for (int nf = 0; nf < 4; ++nf)
    wb[nf] = w + (size_t)(wc + nf * 16 + ll) * MD + lh * 8;

  bf16x8 bcur[4][2], bnxt[4][2];

#define STAGE_A(KT, BUF)                                                      \
  { _Pragma("unroll")                                                         \
    for (int c = 0; c < 4; ++c)                                               \
      cp16(lds[BUF] + abase[c], asrc[c] + (KT) * 64); }

#define LOAD_B(KT)                                                            \
  { _Pragma("unroll")                                                         \
    for (int nf = 0; nf < 4; ++nf)                                            \
      _Pragma("unroll")                                                       \
      for (int kk = 0; kk < 2; ++kk)                                          \
        bnxt[nf][kk] = *reinterpret_cast<const bf16x8*>(                      \
            wb[nf] + (KT) * 64 + kk * 32); }

  // prologue: stage tile 0, prefetch B tile 0
  STAGE_A(0, 0);
  LOAD_B(0);

  const int r0 = wr + ll;          // A fragment row base for mi=0
  const int r1 = wr + 16 + ll;     // mi=1

  for (int kt = 0; kt < 16; ++kt) {
    const int cur = kt & 1;
    // rotate B prefetch into cur (compiler waits its own vmcnt for bnxt)
#pragma unroll
    for (int nf = 0; nf < 4; ++nf)
#pragma unroll
      for (int kk = 0; kk < 2; ++kk) bcur[nf][kk] = bnxt[nf][kk];

    if (kt < 15) {
      STAGE_A(kt + 1, cur ^ 1);    // 4 gl_lds, stay in flight across barriers
      LOAD_B(kt + 1);              // 8 reg loads, in flight across barriers
      asm volatile("s_waitcnt vmcnt(12)" ::: "memory");  // old A done
    } else {
      asm volatile("s_waitcnt vmcnt(0)" ::: "memory");
    }
    __builtin_amdgcn_sched_barrier(0);
    __builtin_amdgcn_s_barrier();
    __builtin_amdgcn_sched_barrier(0);

    // ---- compute tile from lds[cur] + bcur ----
    {
      char* Afb = lds[cur];
#pragma unroll
      for (int kk = 0; kk < 2; ++kk) {
        const int s0 = kk * 8 + lh * 2;
        bf16x8 af[2];
#pragma unroll
        for (int mi = 0; mi < 2; ++mi) {
          const int r = mi ? r1 : r0;
          f32x4 a0 = *reinterpret_cast<f32x4*>(
              Afb + r * 256 + (((s0    ) ^ (r & 15)) << 4));
          f32x4 a1 = *reinterpret_cast<f32x4*>(
              Afb + r * 256 + (((s0 + 1) ^ (r & 15)) << 4));
#pragma unroll
          for (int j = 0; j < 4; ++j) {
            af[mi][j]     = (short)f2b(a0[j]);
            af[mi][4 + j] = (short)f2b(a1[j]);
          }
        }
#pragma unroll
        for (int mi = 0; mi < 2; ++mi)
#pragma unroll
          for (int nf = 0; nf < 4; ++nf)
            acc[mi][nf] = __builtin_amdgcn_mfma_f32_16x16x32_bf16(
                af[mi], bcur[nf][kk], acc[mi][nf], 0, 0, 0);
      }
    }
    __builtin_amdgcn_sched_barrier(0);
    __builtin_amdgcn_s_barrier();
    __builtin_amdgcn_sched_barrier(0);
  }
#undef STAGE_A
#undef LOAD_B

  // ---- epilogue ----
  if (proj < 2) {
    __hip_bfloat16* __restrict__ outp = proj ? k_ws : q_ws;
#pragma unroll
    for (int mi = 0; mi < 2; ++mi)
#pragma unroll
      for (int nf = 0; nf < 4; ++nf) {
        int col = wc + nf * 16 + ll;
#pragma unroll
        for (int q = 0; q < 4; ++q) {
          int row = m0 + wr + mi * 16 + lh * 4 + q;
          union { __hip_bfloat16 h; unsigned short u; } c;
          c.u = (unsigned short)f2b(acc[mi][nf][q]);
          outp[(size_t)row * DH + col] = c.h;
        }
      }
  } else {
    // V transposed: vt[b][d][s], 4 consecutive s per lane -> 8B store
    const int b = m0 >> 11, sb = m0 & 2047;
#pragma unroll
    for (int mi = 0; mi < 2; ++mi)
#pragma unroll
      for (int nf = 0; nf < 4; ++nf) {
        int s = sb + wr + mi * 16 + lh * 4;
        int d = wc + nf * 16 + ll;
        u32x2 pk;
        pk[0] = f2b(acc[mi][nf][0]) | (f2b(acc[mi][nf][1]) << 16);
        pk[1] = f2b(acc[mi][nf][2]) | (f2b(acc[mi][nf][3]) << 16);
        *reinterpret_cast<u32x2*>(&vt_ws[((size_t)b * DH + d) * SEQ + s]) = pk;
      }
  }
}

// ---------------------------------------------------------------------------
// Split-KV causal flash attention (unchanged from Round 4).
// ---------------------------------------------------------------------------
__global__ __launch_bounds__(256) void attn_kernel(
    const __hip_bfloat16* __restrict__ q_ws, const __hip_bfloat16* __restrict__ k_ws,
    const __hip_bfloat16* __restrict__ vt_ws,
    float* __restrict__ pO, float* __restrict__ pml)
{
  const int s = blockIdx.x;
  int qt, c;
  if (s < 8)       { qt = s;                c = 0; }
  else if (s < 24) { int u = s - 8;  qt = 8 + (u >> 1);  c = u & 1; }
  else if (s < 48) { int u = s - 24; qt = 16 + u / 3;    c = u % 3; }
  else             { int u = s - 48; qt = 24 + (u >> 2); c = u & 3; }
  const int b = blockIdx.y;
  const int g = qt >> 3;
  const int slot = b * 80 + (4 * g * (g + 1) + (g + 1) * (qt & 7)) + c;

  const int tid = threadIdx.x;
  const int lane = tid & 63;
  const int wid = tid >> 6;
  const int ll = lane & 15;
  const int lh = lane >> 4;

  __shared__ __hip_bfloat16 Ks[64 * 128];
  __shared__ __hip_bfloat16 Vs[128 * 64];
  __shared__ float Ps[64 * 64];
  char* Ksb = (char*)Ks;
  char* Vsb = (char*)Vs;
  char* Psb = (char*)Ps;

  bf16x8 qf[4];
  {
    const size_t qbase = ((size_t)b * SEQ + qt * 64 + wid * 16 + ll) * DH;
#pragma unroll
    for (int kk = 0; kk < 4; ++kk)
      qf[kk] = *reinterpret_cast<const bf16x8*>(&q_ws[qbase + kk * 32 + lh * 8]);
  }

  const f32x4 zero4 = {0.f, 0.f, 0.f, 0.f};
  float m_r[4], l_r[4];
  f32x4 oacc[8];
#pragma unroll
  for (int q = 0; q < 4; ++q) { m_r[q] = -INFINITY; l_r[q] = 0.f; }
#pragma unroll
  for (int nd = 0; nd < 8; ++nd) oacc[nd] = zero4;

  const float sl2e = 0.0883883476483184f * 1.4426950408889634f;

  const int it0 = c * 8;
  const int it1 = min(qt + 1, it0 + 8);
  for (int it = it0; it < it1; ++it) {
    const int kv0 = it * 64;
#pragma unroll
    for (int i = 0; i < 4; ++i) {
      int id = tid + i * 256;
      int row = id >> 4;
      int cb = (id & 15) << 4;
      u32x4 v = *reinterpret_cast<const u32x4*>(
          &k_ws[((size_t)b * SEQ + kv0 + row) * DH + (cb >> 1)]);
      *reinterpret_cast<u32x4*>(Ksb + row * 256 + (cb ^ ((row & 7) << 4))) = v;
    }
#pragma unroll
    for (int i = 0; i < 4; ++i) {
      int id = tid + i * 256;
      int d = id >> 3;
      int cb = (id & 7) << 4;
      u32x4 v = *reinterpret_cast<const u32x4*>(
          &vt_ws[((size_t)b * DH + d) * SEQ + kv0 + (cb >> 1)]);
      *reinterpret_cast<u32x4*>(Vsb + d * 128 + (cb ^ ((d & 7) << 4))) = v;
    }
    __syncthreads();

    f32x4 sacc[4];
#pragma unroll
    for (int nf = 0; nf < 4; ++nf) sacc[nf] = zero4;
#pragma unroll
    for (int nf = 0; nf < 4; ++nf) {
      int row = nf * 16 + ll;
#pragma unroll
      for (int kk = 0; kk < 4; ++kk) {
        bf16x8 kf = *reinterpret_cast<bf16x8*>(
            Ksb + row * 256 + ((kk * 64 + lh * 16) ^ ((row & 7) << 4)));
        sacc[nf] = __builtin_amdgcn_mfma_f32_16x16x32_bf16(qf[kk], kf, sacc[nf], 0, 0, 0);
      }
    }

    float sv[4][4];
    const int qr0 = qt * 64 + wid * 16 + lh * 4;
#pragma unroll
    for (int nf = 0; nf < 4; ++nf) {
      int kc = kv0 + nf * 16 + ll;
#pragma unroll
      for (int q = 0; q < 4; ++q) {
        float sc = sacc[nf][q] * sl2e;
        sv[nf][q] = (kc <= qr0 + q) ? sc : -INFINITY;
      }
    }

    float p[4][4];
    float alpha[4];
#pragma unroll
    for (int q = 0; q < 4; ++q) {
      float mx = fmaxf(fmaxf(sv[0][q], sv[1][q]), fmaxf(sv[2][q], sv[3][q]));
#pragma unroll
      for (int off = 1; off < 16; off <<= 1)
        mx = fmaxf(mx, __shfl_xor(mx, off));
      float mnew = fmaxf(m_r[q], mx);
      float sum = 0.f;
#pragma unroll
      for (int nf = 0; nf < 4; ++nf) {
        float pv = exp2f(sv[nf][q] - mnew);
        p[nf][q] = pv;
        sum += pv;
      }
#pragma unroll
      for (int off = 1; off < 16; off <<= 1)
        sum += __shfl_xor(sum, off);
      alpha[q] = exp2f(m_r[q] - mnew);
      l_r[q] = l_r[q] * alpha[q] + sum;
      m_r[q] = mnew;
    }
#pragma unroll
    for (int nd = 0; nd < 8; ++nd)
#pragma unroll
      for (int q = 0; q < 4; ++q) oacc[nd][q] *= alpha[q];

#pragma unroll
    for (int nf = 0; nf < 4; ++nf) {
      int kv = nf * 16 + ll;
      f32x4 pv4 = {p[nf][0], p[nf][1], p[nf][2], p[nf][3]};
      *reinterpret_cast<f32x4*>(
          Psb + kv * 256 + ((wid * 64 + lh * 16) ^ ((kv & 7) << 4))) = pv4;
    }

#pragma unroll
    for (int kf = 0; kf < 2; ++kf) {
      float pf[8];
#pragma unroll
      for (int j = 0; j < 8; ++j) {
        int kv = kf * 32 + lh * 8 + j;
        pf[j] = *reinterpret_cast<float*>(
            Psb + kv * 256 + ((wid * 64 + ll * 4) ^ ((kv & 7) << 4)));
      }
      bf16x8 pa;
#pragma unroll
      for (int j = 0; j < 8; ++j) pa[j] = (short)f2b(pf[j]);
#pragma unroll
      for (int nd = 0; nd < 8; ++nd) {
        int d = nd * 16 + ll;
        bf16x8 vf = *reinterpret_cast<bf16x8*>(
            Vsb + d * 128 + ((kf * 64 + lh * 16) ^ ((d & 7) << 4)));
        oacc[nd] = __builtin_amdgcn_mfma_f32_16x16x32_bf16(pa, vf, oacc[nd], 0, 0, 0);
      }
    }
    __syncthreads();
  }

  float* __restrict__ po = pO + (size_t)slot * (64 * 128);
#pragma unroll
  for (int nd = 0; nd < 8; ++nd) {
    int d = nd * 16 + ll;
#pragma unroll
    for (int q = 0; q < 4; ++q) {
      int row = wid * 16 + lh * 4 + q;
      po[row * 128 + d] = oacc[nd][q];
    }
  }
  if (ll == 0) {
    float* __restrict__ pm = pml + (size_t)slot * 128;
#pragma unroll
    for (int q = 0; q < 4; ++q) {
      int row = wid * 16 + lh * 4 + q;
      pm[row * 2 + 0] = m_r[q];
      pm[row * 2 + 1] = l_r[q];
    }
  }
}

// ---------------------------------------------------------------------------
// Combine: merge <=4 partials per (b, qt) with log-sum-exp weights.
// ---------------------------------------------------------------------------
__global__ __launch_bounds__(256) void combine_kernel(
    const float* __restrict__ pO, const float* __restrict__ pml,
    float* __restrict__ out)
{
  const int qt = blockIdx.x;
  const int b = blockIdx.y;
  const int g = qt >> 3;
  const int nc = g + 1;
  const size_t slot0 = (size_t)b * 80 + (4 * g * (g + 1) + (g + 1) * (qt & 7));
  const int tid = threadIdx.x;
  const int r = tid >> 2;
  const int q4 = tid & 3;

  float m[4], l[4];
#pragma unroll
  for (int i = 0; i < 4; ++i) {
    if (i < nc) {
      m[i] = pml[(slot0 + i) * 128 + r * 2 + 0];
      l[i] = pml[(slot0 + i) * 128 + r * 2 + 1];
    } else { m[i] = -INFINITY; l[i] = 0.f; }
  }
  float M = fmaxf(fmaxf(m[0], m[1]), fmaxf(m[2], m[3]));
  float w[4];
  float L = 0.f;
#pragma unroll
  for (int i = 0; i < 4; ++i) {
    w[i] = (i < nc) ? exp2f(m[i] - M) : 0.f;
    L += l[i] * w[i];
  }
  const float inv = 1.0f / L;

  const size_t orow = ((size_t)b * SEQ + qt * 64 + r) * DH;
#pragma unroll
  for (int j = 0; j < 8; ++j) {
    const int col = q4 * 32 + j * 4;
    f32x4 acc = {0.f, 0.f, 0.f, 0.f};
#pragma unroll
    for (int i = 0; i < 4; ++i) {
      if (i < nc) {
        f32x4 v = *reinterpret_cast<const f32x4*>(
            &pO[(slot0 + i) * (64 * 128) + r * 128 + col]);
#pragma unroll
        for (int u = 0; u < 4; ++u) acc[u] += v[u] * w[i];
      }
    }
#pragma unroll
    for (int u = 0; u < 4; ++u) acc[u] *= inv;
    *reinterpret_cast<f32x4*>(&out[orow + col]) = acc;
  }
}

extern "C" void kernel_launch(void* const* d_in, const int* in_sizes, int n_in,
                              void* d_out, int out_size, void* d_ws, size_t ws_size,
                              hipStream_t stream) {
  const float* xq = (const float*)d_in[0];
  const float* xk = (const float*)d_in[1];
  const float* xv = (const float*)d_in[2];
  const float* wq = (const float*)d_in[3];
  const float* wk = (const float*)d_in[4];
  const float* wv = (const float*)d_in[5];

  __hip_bfloat16* q_ws = (__hip_bfloat16*)d_ws;
  __hip_bfloat16* k_ws = q_ws + (size_t)16384 * 128;
  __hip_bfloat16* vt_ws = k_ws + (size_t)16384 * 128;
  __hip_bfloat16* wt_ws = vt_ws + (size_t)16384 * 128;
  float* pO = (float*)((char*)d_ws + 13369344);             // 640*64*128 f32
  float* pml = (float*)((char*)d_ws + 13369344 + 20971520); // 640*64*2 f32
  float* out = (float*)d_out;

  wprep_kernel<<<dim3(3, 8), 256, 0, stream>>>(wq, wk, wv, wt_ws);
  proj_kernel<<<dim3(256, 3), 256, 0, stream>>>(xq, xk, xv, wt_ws,
                                                q_ws, k_ws, vt_ws);
  attn_kernel<<<dim3(80, 8), 256, 0, stream>>>(q_ws, k_ws, vt_ws, pO, pml);
  combine_kernel<<<dim3(32, 8), 256, 0, stream>>>(pO, pml, out);
}